// Round 4
// baseline (57.693 us; speedup 1.0000x reference)
//
#include <hip/hip_runtime.h>

// dist[b,k,n] = sqrt(max(||m||^2 + ||c||^2 - 2 c.m, 0))
// M: (B=4, D=8, N=65536) f32, centroids: (K=256, D=8) f32, out: (B,K,N) f32.
// Store-BW bound: 268 MB output. KCHUNK=32 -> 2048 blocks = 8 blocks/CU =
// 32 waves/CU (residency cap) with half the M read-amplification of KCHUNK=16
// (64 MB total reads). Nontemporal float4 stores keep the 268 MB write stream
// from thrashing L2/L3 so M re-reads stay cache-resident. LDS stages
// c2 = -2*c and ||c||^2; inner loop: acc = msq + csq; 8 fma; v_sqrt(max).

typedef float f32x4 __attribute__((ext_vector_type(4)));  // native vector for
                                                          // __builtin_nontemporal_store

constexpr int B = 4;
constexpr int D = 8;
constexpr int N = 65536;
constexpr int K = 256;
constexpr int VEC = 4;
constexpr int TPB = 256;
constexpr int KCHUNK = 32;
constexpr int NBLK_X = N / (TPB * VEC);  // 64

__global__ __launch_bounds__(TPB) void ComputeDistances_82317343195698_kernel(
    const float* __restrict__ M, const float* __restrict__ C,
    float* __restrict__ out) {
  __shared__ float sc2[KCHUNK][D];  // -2 * c[k][d]
  __shared__ float scsq[KCHUNK];    // ||c[k]||^2

  const int tid = threadIdx.x;
  const int b = blockIdx.y;
  const int k0 = blockIdx.z * KCHUNK;

  if (tid < KCHUNK) {
    const float4* c4 = reinterpret_cast<const float4*>(C + (size_t)(k0 + tid) * D);
    float4 a = c4[0];
    float4 e = c4[1];
    scsq[tid] = a.x * a.x + a.y * a.y + a.z * a.z + a.w * a.w +
                e.x * e.x + e.y * e.y + e.z * e.z + e.w * e.w;
    sc2[tid][0] = -2.f * a.x; sc2[tid][1] = -2.f * a.y;
    sc2[tid][2] = -2.f * a.z; sc2[tid][3] = -2.f * a.w;
    sc2[tid][4] = -2.f * e.x; sc2[tid][5] = -2.f * e.y;
    sc2[tid][6] = -2.f * e.z; sc2[tid][7] = -2.f * e.w;
  }
  __syncthreads();

  const int n0 = (blockIdx.x * TPB + tid) * VEC;

  // Load this thread's 4 columns of M and their squared norms.
  float m[D][VEC];
  float msq[VEC] = {0.f, 0.f, 0.f, 0.f};
#pragma unroll
  for (int d = 0; d < D; ++d) {
    float4 v = *reinterpret_cast<const float4*>(M + ((size_t)(b * D + d) * N + n0));
    m[d][0] = v.x; m[d][1] = v.y; m[d][2] = v.z; m[d][3] = v.w;
#pragma unroll
    for (int j = 0; j < VEC; ++j) msq[j] = fmaf(m[d][j], m[d][j], msq[j]);
  }

  float* outp = out + ((size_t)(b * K + k0) * N + n0);

  // Stagger each block's k-sweep phase so concurrent stores don't all hit the
  // same offset of 256KB-aligned planes simultaneously.
  const int phase = (blockIdx.x + NBLK_X * blockIdx.y + 5 * blockIdx.z) & (KCHUNK - 1);

#pragma unroll 4
  for (int i = 0; i < KCHUNK; ++i) {
    const int kk = (i + phase) & (KCHUNK - 1);
    float c[D];
#pragma unroll
    for (int d = 0; d < D; ++d) c[d] = sc2[kk][d];  // wave-uniform LDS broadcast
    const float cs = scsq[kk];

    f32x4 r;
#pragma unroll
    for (int j = 0; j < VEC; ++j) {
      float acc = msq[j] + cs;
#pragma unroll
      for (int d = 0; d < D; ++d) acc = fmaf(c[d], m[d][j], acc);
      r[j] = __builtin_amdgcn_sqrtf(fmaxf(acc, 0.f));
    }
    __builtin_nontemporal_store(r, reinterpret_cast<f32x4*>(outp + (size_t)kk * N));
  }
}

extern "C" void kernel_launch(void* const* d_in, const int* in_sizes, int n_in,
                              void* d_out, int out_size, void* d_ws, size_t ws_size,
                              hipStream_t stream) {
  const float* M = (const float*)d_in[0];
  const float* C = (const float*)d_in[1];
  float* out = (float*)d_out;

  dim3 grid(NBLK_X, B, K / KCHUNK);  // (64, 4, 8) = 2048 blocks
  dim3 block(TPB);
  ComputeDistances_82317343195698_kernel<<<grid, block, 0, stream>>>(M, C, out);
}

// Round 5
// 48.150 us; speedup vs baseline: 1.1982x; 1.1982x over previous
//
#include <hip/hip_runtime.h>

// dist[b,k,n] = sqrt(max(||m||^2 + ||c||^2 - 2 c.m, 0))
// M: (B=4, D=8, N=65536) f32, centroids: (K=256, D=8) f32, out: (B,K,N) f32.
// Store-BW bound: 268 MB output; fillBuffer evidence shows 6.9 TB/s write BW
// at 10% occupancy, so residency is NOT the lever. KCHUNK=64 (grid 1024,
// 16 waves/CU) cuts M re-reads to 32 MB. Phase stagger keyed on (y,z) ONLY:
// the 64 x-adjacent blocks of each (y,z) group stay in lockstep and write one
// contiguous 256 KB plane at a time (16 fill-like streams). Plain stores
// (nontemporal regressed in R3). LDS stages c2=-2c and ||c||^2; inner loop:
// acc = msq+csq; 8 fma; v_sqrt(max).

constexpr int B = 4;
constexpr int D = 8;
constexpr int N = 65536;
constexpr int K = 256;
constexpr int VEC = 4;
constexpr int TPB = 256;
constexpr int KCHUNK = 64;
constexpr int NBLK_X = N / (TPB * VEC);  // 64

__global__ __launch_bounds__(TPB) void ComputeDistances_82317343195698_kernel(
    const float* __restrict__ M, const float* __restrict__ C,
    float* __restrict__ out) {
  __shared__ float sc2[KCHUNK][D];  // -2 * c[k][d]
  __shared__ float scsq[KCHUNK];    // ||c[k]||^2

  const int tid = threadIdx.x;
  const int b = blockIdx.y;
  const int k0 = blockIdx.z * KCHUNK;

  if (tid < KCHUNK) {
    const float4* c4 = reinterpret_cast<const float4*>(C + (size_t)(k0 + tid) * D);
    float4 a = c4[0];
    float4 e = c4[1];
    scsq[tid] = a.x * a.x + a.y * a.y + a.z * a.z + a.w * a.w +
                e.x * e.x + e.y * e.y + e.z * e.z + e.w * e.w;
    sc2[tid][0] = -2.f * a.x; sc2[tid][1] = -2.f * a.y;
    sc2[tid][2] = -2.f * a.z; sc2[tid][3] = -2.f * a.w;
    sc2[tid][4] = -2.f * e.x; sc2[tid][5] = -2.f * e.y;
    sc2[tid][6] = -2.f * e.z; sc2[tid][7] = -2.f * e.w;
  }
  __syncthreads();

  const int n0 = (blockIdx.x * TPB + tid) * VEC;

  // Load this thread's 4 columns of M and their squared norms.
  float m[D][VEC];
  float msq[VEC] = {0.f, 0.f, 0.f, 0.f};
#pragma unroll
  for (int d = 0; d < D; ++d) {
    float4 v = *reinterpret_cast<const float4*>(M + ((size_t)(b * D + d) * N + n0));
    m[d][0] = v.x; m[d][1] = v.y; m[d][2] = v.z; m[d][3] = v.w;
#pragma unroll
    for (int j = 0; j < VEC; ++j) msq[j] = fmaf(m[d][j], m[d][j], msq[j]);
  }

  float* outp = out + ((size_t)(b * K + k0) * N + n0);

  // Stagger keyed on (y,z) ONLY: x-adjacent blocks stay in lockstep, writing
  // contiguous planes; 16 (y,z) groups start at decorrelated k-offsets.
  const int phase = (blockIdx.z * 17 + blockIdx.y * 4) & (KCHUNK - 1);

#pragma unroll 8
  for (int i = 0; i < KCHUNK; ++i) {
    const int kk = (i + phase) & (KCHUNK - 1);
    float c[D];
#pragma unroll
    for (int d = 0; d < D; ++d) c[d] = sc2[kk][d];  // wave-uniform LDS broadcast
    const float cs = scsq[kk];

    float4 r;
    float* rp = &r.x;
#pragma unroll
    for (int j = 0; j < VEC; ++j) {
      float acc = msq[j] + cs;
#pragma unroll
      for (int d = 0; d < D; ++d) acc = fmaf(c[d], m[d][j], acc);
      rp[j] = __builtin_amdgcn_sqrtf(fmaxf(acc, 0.f));
    }
    *reinterpret_cast<float4*>(outp + (size_t)kk * N) = r;
  }
}

extern "C" void kernel_launch(void* const* d_in, const int* in_sizes, int n_in,
                              void* d_out, int out_size, void* d_ws, size_t ws_size,
                              hipStream_t stream) {
  const float* M = (const float*)d_in[0];
  const float* C = (const float*)d_in[1];
  float* out = (float*)d_out;

  dim3 grid(NBLK_X, B, K / KCHUNK);  // (64, 4, 4) = 1024 blocks
  dim3 block(TPB);
  ComputeDistances_82317343195698_kernel<<<grid, block, 0, stream>>>(M, C, out);
}